// Round 17
// baseline (159.177 us; speedup 1.0000x reference)
//
#include <hip/hip_runtime.h>
#include <hip/hip_bf16.h>
#include <math.h>

#define B_   8
#define T_   2048
#define C_   1024
#define HS_  64
#define MTOT (B_*T_)          // 16384 rows

typedef __attribute__((ext_vector_type(8))) short bf16x8;           // MFMA A/B
typedef __attribute__((ext_vector_type(4))) float f32x4;            // MFMA C/D
typedef __attribute__((ext_vector_type(8))) unsigned short u16x8;   // 16B store

static __device__ __forceinline__ unsigned short f2bf(float f) {
    __hip_bfloat16 h = __float2bfloat16(f);
    return *reinterpret_cast<unsigned short*>(&h);
}

// ---------------------------------------------------------------------------
// Kernel 0: cast W -> bf16 in FRAGMENT ORDER Wf: chunk (fg, kc, kk) of
// 64 lanes x 16B, lane l holds Wt[(fg/3)*48 + (fg%3)*16 + (l&15)]
//                              [kc*64 + kk*32 + (l>>4)*8 .. +7]
// (fg = cg*3+sub indexes the per-wave B-fragment row groups).  Q section
// pre-scaled by C^-0.5 * log2(e) (softmax runs in exp2 domain).
// Proj then loads B-frags as single coalesced 16B/lane L2 reads — no LDS.
// ---------------------------------------------------------------------------
__global__ __launch_bounds__(256) void cast_w_kernel(
    const float* __restrict__ Wq, const float* __restrict__ Wk,
    const float* __restrict__ Wv, unsigned short* __restrict__ Wf)
{
    const int gtid  = blockIdx.x * 256 + threadIdx.x;   // [0, 24576)
    const int lane  = gtid & 63;
    const int chunk = gtid >> 6;                        // [0, 384)
    const int kk    = chunk & 1;
    const int kc    = (chunk >> 1) & 15;
    const int fg    = chunk >> 5;                       // [0, 12)

    const int nrow = (fg / 3) * 48 + (fg % 3) * 16 + (lane & 15);
    const int mat  = nrow >> 6;                         // 0=q 1=k 2=v
    const int col  = nrow & 63;
    const int kb   = kc * 64 + kk * 32 + (lane >> 4) * 8;

    const float* __restrict__ W = (mat == 0) ? Wq : (mat == 1) ? Wk : Wv;
    const float s = (mat == 0) ? 0.03125f * 1.44269504f : 1.0f;  // C^-0.5 * log2e

    u16x8 o;
#pragma unroll
    for (int i = 0; i < 8; ++i)
        o[i] = f2bf(W[(size_t)(kb + i) * HS_ + col] * s);
    *(u16x8*)&Wf[(size_t)gtid * 8] = o;
}

// ---------------------------------------------------------------------------
// Kernel 1: FUSED QKV projection via bf16 MFMA.  NEW: B-fragments load
// DIRECTLY from fragment-ordered Wf (L2-resident) into registers — the
// entire B LDS round-trip (staging writes + frag reads, ~70% of proj's LDS
// bytes) is gone.  B double-set register prefetch one k-iter ahead
// ([kc&1] pattern validated r11).  A keeps depth-2 LDS staging (HBM).
// ---------------------------------------------------------------------------
__global__ __launch_bounds__(512) void proj_gemm(
    const float* __restrict__ x, const unsigned short* __restrict__ Wf,
    unsigned short* __restrict__ qbf, unsigned short* __restrict__ kbf,
    unsigned short* __restrict__ vtbf)
{
    __shared__ unsigned short Als[2][64][72];    // A tile [row][k] (only LDS)

    const int tid  = threadIdx.x;
    const int lane = tid & 63;
    const int wv   = tid >> 6;        // 0..7
    const int wr   = wv & 1;          // row half (32)
    const int cg   = wv >> 1;         // col group: cols cg*48 .. +47
    const int g    = lane >> 4;
    const int n15  = lane & 15;
    const int g4   = g * 4;
    const int m0   = blockIdx.x * 64;

    const int srow = tid >> 3;        // 0..63
    const int seg  = (tid & 7) * 8;
    const float* __restrict__ xrow = &x[(size_t)(m0 + srow) * C_ + seg];

    f32x4 acc[2][3];
#pragma unroll
    for (int i = 0; i < 2; ++i)
#pragma unroll
        for (int j = 0; j < 3; ++j) acc[i][j] = (f32x4){0.f, 0.f, 0.f, 0.f};

    float4 a0[2], a1[2];              // A prefetch regsets (depth 2)
    bf16x8 b0k0[2], b1k0[2], b2k0[2]; // B frag sets (kk=0), indexed kc&1
    bf16x8 b0k1[2], b1k1[2], b2k1[2]; // B frag sets (kk=1)

#define PROJ_LOAD_A(KC, S)                                              \
    do {                                                                \
        a0[S] = *(const float4*)&xrow[(KC) * 64 + 0];                   \
        a1[S] = *(const float4*)&xrow[(KC) * 64 + 4];                   \
    } while (0)

    // Wf chunk addr (ushorts): ((fg*32 + kc*2 + kk)*64 + lane) * 8
#define PROJ_LOAD_BF(KC, S)                                                       \
    do {                                                                          \
        b0k0[S] = *(const bf16x8*)&Wf[(size_t)(((cg*3+0)*32 + (KC)*2 + 0)*64 + lane)*8]; \
        b1k0[S] = *(const bf16x8*)&Wf[(size_t)(((cg*3+1)*32 + (KC)*2 + 0)*64 + lane)*8]; \
        b2k0[S] = *(const bf16x8*)&Wf[(size_t)(((cg*3+2)*32 + (KC)*2 + 0)*64 + lane)*8]; \
        b0k1[S] = *(const bf16x8*)&Wf[(size_t)(((cg*3+0)*32 + (KC)*2 + 1)*64 + lane)*8]; \
        b1k1[S] = *(const bf16x8*)&Wf[(size_t)(((cg*3+1)*32 + (KC)*2 + 1)*64 + lane)*8]; \
        b2k1[S] = *(const bf16x8*)&Wf[(size_t)(((cg*3+2)*32 + (KC)*2 + 1)*64 + lane)*8]; \
    } while (0)

#define PROJ_WRITE_A(BUF, S)                                            \
    do {                                                                \
        u16x8 v0;                                                       \
        v0[0]=f2bf(a0[S].x); v0[1]=f2bf(a0[S].y);                       \
        v0[2]=f2bf(a0[S].z); v0[3]=f2bf(a0[S].w);                       \
        v0[4]=f2bf(a1[S].x); v0[5]=f2bf(a1[S].y);                       \
        v0[6]=f2bf(a1[S].z); v0[7]=f2bf(a1[S].w);                       \
        *(u16x8*)&Als[BUF][srow][seg] = v0;                             \
    } while (0)

    PROJ_LOAD_A(0, 0);
    PROJ_LOAD_BF(0, 0);
    PROJ_WRITE_A(0, 0);
    PROJ_LOAD_A(1, 1);
    __syncthreads();

    const int NK = C_ / 64;           // 16
    for (int kc = 0; kc < NK; ++kc) {
        const int cur = kc & 1;
        const int ka  = (kc + 2 < NK) ? kc + 2 : NK - 1;   // A: depth 2
        const int kb  = (kc + 1 < NK) ? kc + 1 : NK - 1;   // B: depth 1
        PROJ_LOAD_A(ka, kc & 1);
        PROJ_LOAD_BF(kb, (kc + 1) & 1);

        // ---- kk = 0 ----
        {
            bf16x8 fa0 = *(const bf16x8*)&Als[cur][wr * 32 + n15][0 * 32 + g * 8];
            bf16x8 fa1 = *(const bf16x8*)&Als[cur][wr * 32 + 16 + n15][0 * 32 + g * 8];
            acc[0][0] = __builtin_amdgcn_mfma_f32_16x16x32_bf16(fa0, b0k0[cur], acc[0][0], 0, 0, 0);
            acc[0][1] = __builtin_amdgcn_mfma_f32_16x16x32_bf16(fa0, b1k0[cur], acc[0][1], 0, 0, 0);
            acc[0][2] = __builtin_amdgcn_mfma_f32_16x16x32_bf16(fa0, b2k0[cur], acc[0][2], 0, 0, 0);
            acc[1][0] = __builtin_amdgcn_mfma_f32_16x16x32_bf16(fa1, b0k0[cur], acc[1][0], 0, 0, 0);
            acc[1][1] = __builtin_amdgcn_mfma_f32_16x16x32_bf16(fa1, b1k0[cur], acc[1][1], 0, 0, 0);
            acc[1][2] = __builtin_amdgcn_mfma_f32_16x16x32_bf16(fa1, b2k0[cur], acc[1][2], 0, 0, 0);
        }
        // ---- kk = 1 ----
        {
            bf16x8 fa0 = *(const bf16x8*)&Als[cur][wr * 32 + n15][1 * 32 + g * 8];
            bf16x8 fa1 = *(const bf16x8*)&Als[cur][wr * 32 + 16 + n15][1 * 32 + g * 8];
            acc[0][0] = __builtin_amdgcn_mfma_f32_16x16x32_bf16(fa0, b0k1[cur], acc[0][0], 0, 0, 0);
            acc[0][1] = __builtin_amdgcn_mfma_f32_16x16x32_bf16(fa0, b1k1[cur], acc[0][1], 0, 0, 0);
            acc[0][2] = __builtin_amdgcn_mfma_f32_16x16x32_bf16(fa0, b2k1[cur], acc[0][2], 0, 0, 0);
            acc[1][0] = __builtin_amdgcn_mfma_f32_16x16x32_bf16(fa1, b0k1[cur], acc[1][0], 0, 0, 0);
            acc[1][1] = __builtin_amdgcn_mfma_f32_16x16x32_bf16(fa1, b1k1[cur], acc[1][1], 0, 0, 0);
            acc[1][2] = __builtin_amdgcn_mfma_f32_16x16x32_bf16(fa1, b2k1[cur], acc[1][2], 0, 0, 0);
        }

        if (kc + 1 < NK) {
            __syncthreads();
            PROJ_WRITE_A(cur ^ 1, (kc + 1) & 1);
            __syncthreads();
        }
    }
#undef PROJ_LOAD_A
#undef PROJ_LOAD_BF
#undef PROJ_WRITE_A

    // ---- epilogue: stage C tile in Als region, then coalesced stores ----
    __syncthreads();
    unsigned short* Cqk = &Als[0][0][0];            // [64][136] = 8704 u16
    unsigned short* Vtr = &Als[0][0][0] + 8704;     // [64][72]  = 4608 u16 (13312 <= 18432)

#pragma unroll
    for (int i = 0; i < 2; ++i)
#pragma unroll
        for (int j = 0; j < 3; ++j) {
            const int gcol = cg * 48 + j * 16 + n15;
            const int row0 = wr * 32 + i * 16 + g4;
            if (gcol < 128) {
#pragma unroll
                for (int r = 0; r < 4; ++r)
                    Cqk[(size_t)(row0 + r) * 136 + gcol] = f2bf(acc[i][j][r]);
            } else {
                ushort4 o;
                o.x = f2bf(acc[i][j][0]); o.y = f2bf(acc[i][j][1]);
                o.z = f2bf(acc[i][j][2]); o.w = f2bf(acc[i][j][3]);
                *(ushort4*)&Vtr[(size_t)(gcol - 128) * 72 + row0] = o;
            }
        }
    __syncthreads();

#pragma unroll
    for (int p = 0; p < 2; ++p) {
        const int flat = tid + p * 512;
        const int mat  = flat >> 9;          // 0=q, 1=k
        const int r64  = (flat >> 3) & 63;
        const int sg   = (flat & 7) * 8;
        unsigned short* __restrict__ dst = mat ? kbf : qbf;
        *(int4*)&dst[(size_t)(m0 + r64) * HS_ + sg] =
            *(const int4*)&Cqk[(size_t)r64 * 136 + mat * 64 + sg];
    }
    {
        const int b  = m0 >> 11;
        const int t0 = m0 & 2047;
        const int hs = tid >> 3;             // 0..63
        *(int4*)&vtbf[((size_t)b * HS_ + hs) * T_ + t0 + seg] =
            *(const int4*)&Vtr[(size_t)hs * 72 + seg];
    }
}

// ---------------------------------------------------------------------------
// Kernel 2: causal flash attention, bf16 MFMA — r15/r16 structure (static-max
// softmax, deferred l-reduce, diagonal-only mask, grid (64,8) complementary
// swizzle).  NEW: the "-16" bias removed entirely — p = exp2(S); the 2^16
// folds exactly into 1/l (O and l scale identically).
// ---------------------------------------------------------------------------
__global__ __launch_bounds__(512) void attn_kernel(
    const unsigned short* __restrict__ qbf,
    const unsigned short* __restrict__ kbf,
    const unsigned short* __restrict__ vtbf,
    float* __restrict__ y)
{
    __shared__ unsigned short KVs[4][64][72];   // [0..1]=K bufs, [2..3]=V bufs

    const int tid  = threadIdx.x;
    const int lane = tid & 63;
    const int wv   = tid >> 6;        // 0..7
    const int rg   = wv & 1;          // query 16-group
    const int h    = (wv >> 1) & 1;   // KV 32-half within tile
    const int tp   = wv >> 2;         // tile parity group
    const int g    = lane >> 4;
    const int n15  = lane & 15;
    const int g4   = g * 4;
    const int b    = blockIdx.y;
    const size_t qkoff = (size_t)b * T_ * HS_;
    const size_t voff  = (size_t)b * HS_ * T_;

    const int sgrp = tid >> 8;        // staging group == its waves' tp
    const int st   = tid & 255;
    const int srow = st >> 3;         // 0..31
    const int soff = (st & 7) * 8;

    const unsigned short* __restrict__ kgb = &kbf[qkoff];
    const unsigned short* __restrict__ vgb = &vtbf[voff];

    // complementary swizzle: co-resident pair (x,y) & (x,y+4) sums to 33 tiles
    const int qbi  = (blockIdx.y < 4) ? (int)blockIdx.x : 63 - (int)blockIdx.x;
    const int q0   = qbi * 32;
    const int qq0  = q0 + rg * 16;
    const int qrow = qq0 + n15;
    const int nkt  = (qbi >> 1) + 1;

    bf16x8 qf0 = *(const bf16x8*)&qbf[qkoff + (size_t)qrow * HS_ + g * 8];
    bf16x8 qf1 = *(const bf16x8*)&qbf[qkoff + (size_t)qrow * HS_ + g * 8 + 32];

    f32x4 o0 = {0.f,0.f,0.f,0.f}, o1 = o0, o2 = o0, o3 = o0;
    float lp = 0.f;                   // per-lane l partial (reduced after loop)

    int4 kr0, kr1, vr0, vr1;
    // prologue: group sgrp stages tile min(sgrp, nkt-1) into buffer sgrp
    {
        int tix = (sgrp < nkt) ? sgrp : nkt - 1;
        kr0 = *(const int4*)&kgb[(size_t)(tix * 64 + srow) * HS_ + soff];
        kr1 = *(const int4*)&kgb[(size_t)(tix * 64 + srow + 32) * HS_ + soff];
        vr0 = *(const int4*)&vgb[(size_t)srow * T_ + tix * 64 + soff];
        vr1 = *(const int4*)&vgb[(size_t)(srow + 32) * T_ + tix * 64 + soff];
    }
    *(int4*)&KVs[sgrp][srow][soff]          = kr0;
    *(int4*)&KVs[sgrp][srow + 32][soff]     = kr1;
    *(int4*)&KVs[2 + sgrp][srow][soff]      = vr0;
    *(int4*)&KVs[2 + sgrp][srow + 32][soff] = vr1;
    __syncthreads();

    const int J = (nkt + 1) >> 1;
    for (int j = 0; j < J; ++j) {
        const int kt = 2 * j + tp;                 // my compute tile
        {
            int tix = 2 * j + sgrp + 2;            // my group's next tile
            if (tix > nkt - 1) tix = nkt - 1;      // clamped
            kr0 = *(const int4*)&kgb[(size_t)(tix * 64 + srow) * HS_ + soff];
            kr1 = *(const int4*)&kgb[(size_t)(tix * 64 + srow + 32) * HS_ + soff];
            vr0 = *(const int4*)&vgb[(size_t)srow * T_ + tix * 64 + soff];
            vr1 = *(const int4*)&vgb[(size_t)(srow + 32) * T_ + tix * 64 + soff];
        }

        if (kt < nkt) {
            const int k0  = kt * 64;
            const int ks0 = h * 32;
            f32x4 st0 = {0.f,0.f,0.f,0.f}, st1 = st0;
            {
                bf16x8 ka;
                ka  = *(const bf16x8*)&KVs[tp][ks0 + n15][g * 8];
                st0 = __builtin_amdgcn_mfma_f32_16x16x32_bf16(ka, qf0, st0, 0, 0, 0);
                ka  = *(const bf16x8*)&KVs[tp][ks0 + n15][g * 8 + 32];
                st0 = __builtin_amdgcn_mfma_f32_16x16x32_bf16(ka, qf1, st0, 0, 0, 0);
                ka  = *(const bf16x8*)&KVs[tp][ks0 + 16 + n15][g * 8];
                st1 = __builtin_amdgcn_mfma_f32_16x16x32_bf16(ka, qf0, st1, 0, 0, 0);
                ka  = *(const bf16x8*)&KVs[tp][ks0 + 16 + n15][g * 8 + 32];
                st1 = __builtin_amdgcn_mfma_f32_16x16x32_bf16(ka, qf1, st1, 0, 0, 0);
            }

            // ---- causal mask: only the diagonal tile needs it ----
            if (kt == nkt - 1) {
                const int kb = k0 + h * 32 + g4;
#pragma unroll
                for (int r = 0; r < 4; ++r) {
                    if (kb + r      > qrow) st0[r] = -INFINITY;
                    if (kb + 16 + r > qrow) st1[r] = -INFINITY;
                }
            }

            // ---- static softmax: p = exp2(S) (scale folded into 1/l) ----
            float p[8];
#pragma unroll
            for (int r = 0; r < 4; ++r) {
                p[r]     = exp2f(st0[r]);
                p[4 + r] = exp2f(st1[r]);
            }
#pragma unroll
            for (int r = 0; r < 8; ++r) lp += p[r];

            bf16x8 pa;
#pragma unroll
            for (int r = 0; r < 4; ++r) {
                pa[r]     = (short)f2bf(p[r]);
                pa[4 + r] = (short)f2bf(p[4 + r]);
            }

            const int kvo = h * 32;
            {
                ushort4 lo, hi; bf16x8 vb;
#define PV_STEP(NT, ONT)                                                        \
                lo = *(const ushort4*)&KVs[2 + tp][(NT)*16 + n15][kvo + g4];    \
                hi = *(const ushort4*)&KVs[2 + tp][(NT)*16 + n15][kvo + 16 + g4];\
                vb[0] = (short)lo.x; vb[1] = (short)lo.y;                       \
                vb[2] = (short)lo.z; vb[3] = (short)lo.w;                       \
                vb[4] = (short)hi.x; vb[5] = (short)hi.y;                       \
                vb[6] = (short)hi.z; vb[7] = (short)hi.w;                       \
                ONT = __builtin_amdgcn_mfma_f32_16x16x32_bf16(pa, vb, ONT, 0, 0, 0);
                PV_STEP(0, o0)
                PV_STEP(1, o1)
                PV_STEP(2, o2)
                PV_STEP(3, o3)
#undef PV_STEP
            }
        }

        if (j + 1 < J) {
            __syncthreads();                 // all readers done with both bufs
            *(int4*)&KVs[sgrp][srow][soff]          = kr0;
            *(int4*)&KVs[sgrp][srow + 32][soff]     = kr1;
            *(int4*)&KVs[2 + sgrp][srow][soff]      = vr0;
            *(int4*)&KVs[2 + sgrp][srow + 32][soff] = vr1;
            __syncthreads();                 // next tiles visible
        }
    }

    // ---- deferred cross-lane l reduce (l is linear in p) ----
    float lrow = lp;
    lrow += __shfl_xor(lrow, 16);
    lrow += __shfl_xor(lrow, 32);

    // ---- 4-way merge: all partials share the (implicit) max -> plain sums ----
    __syncthreads();                          // all compute done; LDS free
    float* FS = (float*)&KVs[0][0][0];        // 9216 floats scratch
    const int pid = (tp << 1) | h;
    if (pid != 0) {
        float* Ob = FS + (pid - 1) * 2176 + rg * 1088;
#pragma unroll
        for (int r = 0; r < 4; ++r) {
            Ob[(g4 + r) * 68 +  0 + n15] = o0[r];
            Ob[(g4 + r) * 68 + 16 + n15] = o1[r];
            Ob[(g4 + r) * 68 + 32 + n15] = o2[r];
            Ob[(g4 + r) * 68 + 48 + n15] = o3[r];
        }
        if (g == 0)
            FS[6528 + (pid - 1) * 32 + rg * 16 + n15] = lrow;
    }
    __syncthreads();
    if (pid == 0) {
        float l1 = FS[6528 +  0 + rg * 16 + n15];
        float l2 = FS[6528 + 32 + rg * 16 + n15];
        float l3 = FS[6528 + 64 + rg * 16 + n15];
        float invl = 1.0f / (lrow + l1 + l2 + l3);   // > 0: pid0 covers diagonal
        const float* O1s = FS;
        const float* O2s = FS + 2176;
        const float* O3s = FS + 4352;
#pragma unroll
        for (int r = 0; r < 4; ++r) {
            float ir = __shfl(invl, g4 + r);
            const int base = rg * 1088 + (g4 + r) * 68 + n15;
            float* yr = &y[((size_t)b * T_ + qq0 + g4 + r) * HS_];
            yr[ 0 + n15] = (o0[r] + O1s[base]      + O2s[base]      + O3s[base]     ) * ir;
            yr[16 + n15] = (o1[r] + O1s[base + 16] + O2s[base + 16] + O3s[base + 16]) * ir;
            yr[32 + n15] = (o2[r] + O1s[base + 32] + O2s[base + 32] + O3s[base + 32]) * ir;
            yr[48 + n15] = (o3[r] + O1s[base + 48] + O2s[base + 48] + O3s[base + 48]) * ir;
        }
    }
}

extern "C" void kernel_launch(void* const* d_in, const int* in_sizes, int n_in,
                              void* d_out, int out_size, void* d_ws, size_t ws_size,
                              hipStream_t stream)
{
    const float* x  = (const float*)d_in[0];
    const float* Wq = (const float*)d_in[1];
    const float* Wk = (const float*)d_in[2];
    const float* Wv = (const float*)d_in[3];

    unsigned short* qbf  = (unsigned short*)d_ws;                 // [B,T,64] bf16 (prescaled, log2e)
    unsigned short* kbf  = qbf + (size_t)MTOT * HS_;              // [B,T,64] bf16
    unsigned short* vtbf = kbf + (size_t)MTOT * HS_;              // [B,64,T] bf16
    unsigned short* Wf   = vtbf + (size_t)MTOT * HS_;             // [384 chunks][64][8] bf16

    cast_w_kernel<<<96, 256, 0, stream>>>(Wq, Wk, Wv, Wf);
    proj_gemm<<<256, 512, 0, stream>>>(x, Wf, qbf, kbf, vtbf);
    attn_kernel<<<dim3(64, B_), 512, 0, stream>>>(qbf, kbf, vtbf, (float*)d_out);
}

// Round 20
// 43.398 us; speedup vs baseline: 3.6678x; 3.6678x over previous
//
#include <hip/hip_runtime.h>
#include <hip/hip_bf16.h>
#include <math.h>

#define B_   8
#define T_   2048
#define C_   1024
#define HS_  64
#define MTOT (B_*T_)          // 16384 rows

typedef __attribute__((ext_vector_type(8))) short bf16x8;           // MFMA A/B
typedef __attribute__((ext_vector_type(4))) float f32x4;            // MFMA C/D
typedef __attribute__((ext_vector_type(8))) unsigned short u16x8;   // 16B store

static __device__ __forceinline__ unsigned short f2bf(float f) {
    __hip_bfloat16 h = __float2bfloat16(f);
    return *reinterpret_cast<unsigned short*>(&h);
}

// ---------------------------------------------------------------------------
// Kernel 0: cast W -> bf16 in FRAGMENT ORDER Wf (validated r16 layout):
// chunk (fg, kc, kk) of 64 lanes x 16B, lane l holds
//   Wt[(fg/3)*48 + (fg%3)*16 + (l&15)][kc*64 + kk*32 + (l>>4)*8 .. +7].
// Q section pre-scaled by C^-0.5 * log2(e).
// ---------------------------------------------------------------------------
__global__ __launch_bounds__(256) void cast_w_kernel(
    const float* __restrict__ Wq, const float* __restrict__ Wk,
    const float* __restrict__ Wv, unsigned short* __restrict__ Wf)
{
    const int gtid  = blockIdx.x * 256 + threadIdx.x;   // [0, 24576)
    const int lane  = gtid & 63;
    const int chunk = gtid >> 6;                        // [0, 384)
    const int kk    = chunk & 1;
    const int kc    = (chunk >> 1) & 15;
    const int fg    = chunk >> 5;                       // [0, 12)

    const int nrow = (fg / 3) * 48 + (fg % 3) * 16 + (lane & 15);
    const int mat  = nrow >> 6;                         // 0=q 1=k 2=v
    const int col  = nrow & 63;
    const int kb   = kc * 64 + kk * 32 + (lane >> 4) * 8;

    const float* __restrict__ W = (mat == 0) ? Wq : (mat == 1) ? Wk : Wv;
    const float s = (mat == 0) ? 0.03125f * 1.44269504f : 1.0f;  // C^-0.5 * log2e

    u16x8 o;
#pragma unroll
    for (int i = 0; i < 8; ++i)
        o[i] = f2bf(W[(size_t)(kb + i) * HS_ + col] * s);
    *(u16x8*)&Wf[(size_t)gtid * 8] = o;
}

// ---------------------------------------------------------------------------
// Kernel 1: FUSED QKV projection via bf16 MFMA.  B-fragments load directly
// from fragment-ordered Wf (L2-resident) — no B LDS round-trip.  Named
// register sets (rule #20).  FIX vs r18: the v-transpose epilogue scratch
// OVERFLOWED the 18.4 KB Als array by 8 KB (ushort/byte conflation) — UB
// that survived r16's codegen and broke r17/r18's.  Now a dedicated
// VtrS[64][72] shared array (LDS 27648 B total, all accesses in-bounds).
// ---------------------------------------------------------------------------
__global__ __launch_bounds__(512) void proj_gemm(
    const float* __restrict__ x, const unsigned short* __restrict__ Wf,
    unsigned short* __restrict__ qbf, unsigned short* __restrict__ kbf,
    unsigned short* __restrict__ vtbf)
{
    __shared__ unsigned short Als[2][64][72];    // A tile [row][k]  (9216 u16)
    __shared__ unsigned short VtrS[64][72];      // epilogue v scratch (4608 u16)

    const int tid  = threadIdx.x;
    const int lane = tid & 63;
    const int wv   = tid >> 6;        // 0..7
    const int wr   = wv & 1;          // row half (32)
    const int cg   = wv >> 1;         // col group: cols cg*48 .. +47
    const int g    = lane >> 4;
    const int n15  = lane & 15;
    const int g4   = g * 4;
    const int m0   = blockIdx.x * 64;

    const int srow = tid >> 3;        // 0..63
    const int seg  = (tid & 7) * 8;
    const float* __restrict__ xrow = &x[(size_t)(m0 + srow) * C_ + seg];
    // per-wave Wf bases (ushort index): fragment rows cg*3+{0,1,2}
    const unsigned short* __restrict__ wf0 = &Wf[(size_t)((cg*3+0)*32*64 + lane)*8];
    const unsigned short* __restrict__ wf1 = &Wf[(size_t)((cg*3+1)*32*64 + lane)*8];
    const unsigned short* __restrict__ wf2 = &Wf[(size_t)((cg*3+2)*32*64 + lane)*8];

    f32x4 acc[2][3];
#pragma unroll
    for (int i = 0; i < 2; ++i)
#pragma unroll
        for (int j = 0; j < 3; ++j) acc[i][j] = (f32x4){0.f, 0.f, 0.f, 0.f};

    float4 a0E, a1E, a0O, a1O;                 // A prefetch (named, depth 2)
    bf16x8 bE00, bE10, bE20, bE01, bE11, bE21; // B frags, even set (kk0, kk1)
    bf16x8 bO00, bO10, bO20, bO01, bO11, bO21; // B frags, odd set

#define LOAD_A(KC, A0, A1)                                              \
    do {                                                                \
        A0 = *(const float4*)&xrow[(KC) * 64 + 0];                      \
        A1 = *(const float4*)&xrow[(KC) * 64 + 4];                      \
    } while (0)

#define LOAD_BF(KC, B00, B10, B20, B01, B11, B21)                       \
    do {                                                                \
        const size_t c0 = (size_t)(KC) * 1024;   /* (KC*2 chunks)*512 */\
        B00 = *(const bf16x8*)&wf0[c0];                                 \
        B10 = *(const bf16x8*)&wf1[c0];                                 \
        B20 = *(const bf16x8*)&wf2[c0];                                 \
        B01 = *(const bf16x8*)&wf0[c0 + 512];                           \
        B11 = *(const bf16x8*)&wf1[c0 + 512];                           \
        B21 = *(const bf16x8*)&wf2[c0 + 512];                           \
    } while (0)

#define WRITE_A(BUF, A0, A1)                                            \
    do {                                                                \
        u16x8 v0;                                                       \
        v0[0]=f2bf((A0).x); v0[1]=f2bf((A0).y);                         \
        v0[2]=f2bf((A0).z); v0[3]=f2bf((A0).w);                         \
        v0[4]=f2bf((A1).x); v0[5]=f2bf((A1).y);                         \
        v0[6]=f2bf((A1).z); v0[7]=f2bf((A1).w);                         \
        *(u16x8*)&Als[BUF][srow][seg] = v0;                             \
    } while (0)

#define COMPUTE(BUF, B00, B10, B20, B01, B11, B21)                                         \
    do {                                                                                   \
        bf16x8 fa0 = *(const bf16x8*)&Als[BUF][wr * 32 + n15][g * 8];                      \
        bf16x8 fa1 = *(const bf16x8*)&Als[BUF][wr * 32 + 16 + n15][g * 8];                 \
        acc[0][0] = __builtin_amdgcn_mfma_f32_16x16x32_bf16(fa0, B00, acc[0][0], 0, 0, 0); \
        acc[0][1] = __builtin_amdgcn_mfma_f32_16x16x32_bf16(fa0, B10, acc[0][1], 0, 0, 0); \
        acc[0][2] = __builtin_amdgcn_mfma_f32_16x16x32_bf16(fa0, B20, acc[0][2], 0, 0, 0); \
        acc[1][0] = __builtin_amdgcn_mfma_f32_16x16x32_bf16(fa1, B00, acc[1][0], 0, 0, 0); \
        acc[1][1] = __builtin_amdgcn_mfma_f32_16x16x32_bf16(fa1, B10, acc[1][1], 0, 0, 0); \
        acc[1][2] = __builtin_amdgcn_mfma_f32_16x16x32_bf16(fa1, B20, acc[1][2], 0, 0, 0); \
        fa0 = *(const bf16x8*)&Als[BUF][wr * 32 + n15][32 + g * 8];                        \
        fa1 = *(const bf16x8*)&Als[BUF][wr * 32 + 16 + n15][32 + g * 8];                   \
        acc[0][0] = __builtin_amdgcn_mfma_f32_16x16x32_bf16(fa0, B01, acc[0][0], 0, 0, 0); \
        acc[0][1] = __builtin_amdgcn_mfma_f32_16x16x32_bf16(fa0, B11, acc[0][1], 0, 0, 0); \
        acc[0][2] = __builtin_amdgcn_mfma_f32_16x16x32_bf16(fa0, B21, acc[0][2], 0, 0, 0); \
        acc[1][0] = __builtin_amdgcn_mfma_f32_16x16x32_bf16(fa1, B01, acc[1][0], 0, 0, 0); \
        acc[1][1] = __builtin_amdgcn_mfma_f32_16x16x32_bf16(fa1, B11, acc[1][1], 0, 0, 0); \
        acc[1][2] = __builtin_amdgcn_mfma_f32_16x16x32_bf16(fa1, B21, acc[1][2], 0, 0, 0); \
    } while (0)

    // prologue: A(0) -> Als[0]; A(1) in flight (odd set); B(0) -> even set
    LOAD_A(0, a0E, a1E);
    LOAD_BF(0, bE00, bE10, bE20, bE01, bE11, bE21);
    WRITE_A(0, a0E, a1E);
    LOAD_A(1, a0O, a1O);
    __syncthreads();

    const int NK = C_ / 64;           // 16 (even)
#pragma unroll 1
    for (int kc = 0; kc < NK; kc += 2) {
        // ---- even body: compute tile kc from Als[0] x bE ----
        {
            const int ka = (kc + 2 < NK) ? kc + 2 : NK - 1;
            LOAD_A(ka, a0E, a1E);
            const int kb = (kc + 1 < NK) ? kc + 1 : NK - 1;
            LOAD_BF(kb, bO00, bO10, bO20, bO01, bO11, bO21);
            COMPUTE(0, bE00, bE10, bE20, bE01, bE11, bE21);
            __syncthreads();                      // readers done with Als[1]
            WRITE_A(1, a0O, a1O);                 // tile kc+1 (loaded prev odd)
            __syncthreads();
        }
        // ---- odd body: compute tile kc+1 from Als[1] x bO ----
        {
            const int ka = (kc + 3 < NK) ? kc + 3 : NK - 1;
            LOAD_A(ka, a0O, a1O);
            const int kb = (kc + 2 < NK) ? kc + 2 : NK - 1;
            LOAD_BF(kb, bE00, bE10, bE20, bE01, bE11, bE21);
            COMPUTE(1, bO00, bO10, bO20, bO01, bO11, bO21);
            if (kc + 2 < NK) {
                __syncthreads();                  // readers done with Als[0]
                WRITE_A(0, a0E, a1E);             // tile kc+2
                __syncthreads();
            }
        }
    }
#undef LOAD_A
#undef LOAD_BF
#undef WRITE_A
#undef COMPUTE

    // ---- epilogue: stage C tile (Cqk in Als: 8704 <= 9216 u16; v in VtrS) ----
    __syncthreads();
    unsigned short* Cqk = &Als[0][0][0];            // [64][136] = 8704 u16 (in-bounds)
    unsigned short* Vtr = &VtrS[0][0];              // [64][72]  = 4608 u16 (dedicated)

#pragma unroll
    for (int i = 0; i < 2; ++i)
#pragma unroll
        for (int j = 0; j < 3; ++j) {
            const int gcol = cg * 48 + j * 16 + n15;
            const int row0 = wr * 32 + i * 16 + g4;
            if (gcol < 128) {
#pragma unroll
                for (int r = 0; r < 4; ++r)
                    Cqk[(size_t)(row0 + r) * 136 + gcol] = f2bf(acc[i][j][r]);
            } else {
                ushort4 o;
                o.x = f2bf(acc[i][j][0]); o.y = f2bf(acc[i][j][1]);
                o.z = f2bf(acc[i][j][2]); o.w = f2bf(acc[i][j][3]);
                *(ushort4*)&Vtr[(size_t)(gcol - 128) * 72 + row0] = o;
            }
        }
    __syncthreads();

#pragma unroll
    for (int p = 0; p < 2; ++p) {
        const int flat = tid + p * 512;
        const int mat  = flat >> 9;          // 0=q, 1=k
        const int r64  = (flat >> 3) & 63;
        const int sg   = (flat & 7) * 8;
        unsigned short* __restrict__ dst = mat ? kbf : qbf;
        *(int4*)&dst[(size_t)(m0 + r64) * HS_ + sg] =
            *(const int4*)&Cqk[(size_t)r64 * 136 + mat * 64 + sg];
    }
    {
        const int b  = m0 >> 11;
        const int t0 = m0 & 2047;
        const int hs = tid >> 3;             // 0..63
        *(int4*)&vtbf[((size_t)b * HS_ + hs) * T_ + t0 + seg] =
            *(const int4*)&Vtr[(size_t)hs * 72 + seg];
    }
}

// ---------------------------------------------------------------------------
// Kernel 2: causal flash attention, bf16 MFMA — r16 structure (validated
// passing in the 159-us run): static softmax p = exp2(S) (scale folded into
// 1/l), deferred l-reduce, diagonal-only mask, grid (64,8) complementary
// swizzle.
// ---------------------------------------------------------------------------
__global__ __launch_bounds__(512) void attn_kernel(
    const unsigned short* __restrict__ qbf,
    const unsigned short* __restrict__ kbf,
    const unsigned short* __restrict__ vtbf,
    float* __restrict__ y)
{
    __shared__ unsigned short KVs[4][64][72];   // [0..1]=K bufs, [2..3]=V bufs

    const int tid  = threadIdx.x;
    const int lane = tid & 63;
    const int wv   = tid >> 6;        // 0..7
    const int rg   = wv & 1;          // query 16-group
    const int h    = (wv >> 1) & 1;   // KV 32-half within tile
    const int tp   = wv >> 2;         // tile parity group
    const int g    = lane >> 4;
    const int n15  = lane & 15;
    const int g4   = g * 4;
    const int b    = blockIdx.y;
    const size_t qkoff = (size_t)b * T_ * HS_;
    const size_t voff  = (size_t)b * HS_ * T_;

    const int sgrp = tid >> 8;        // staging group == its waves' tp
    const int st   = tid & 255;
    const int srow = st >> 3;         // 0..31
    const int soff = (st & 7) * 8;

    const unsigned short* __restrict__ kgb = &kbf[qkoff];
    const unsigned short* __restrict__ vgb = &vtbf[voff];

    // complementary swizzle: co-resident pair (x,y) & (x,y+4) sums to 33 tiles
    const int qbi  = (blockIdx.y < 4) ? (int)blockIdx.x : 63 - (int)blockIdx.x;
    const int q0   = qbi * 32;
    const int qq0  = q0 + rg * 16;
    const int qrow = qq0 + n15;
    const int nkt  = (qbi >> 1) + 1;

    bf16x8 qf0 = *(const bf16x8*)&qbf[qkoff + (size_t)qrow * HS_ + g * 8];
    bf16x8 qf1 = *(const bf16x8*)&qbf[qkoff + (size_t)qrow * HS_ + g * 8 + 32];

    f32x4 o0 = {0.f,0.f,0.f,0.f}, o1 = o0, o2 = o0, o3 = o0;
    float lp = 0.f;                   // per-lane l partial (reduced after loop)

    int4 kr0, kr1, vr0, vr1;
    // prologue: group sgrp stages tile min(sgrp, nkt-1) into buffer sgrp
    {
        int tix = (sgrp < nkt) ? sgrp : nkt - 1;
        kr0 = *(const int4*)&kgb[(size_t)(tix * 64 + srow) * HS_ + soff];
        kr1 = *(const int4*)&kgb[(size_t)(tix * 64 + srow + 32) * HS_ + soff];
        vr0 = *(const int4*)&vgb[(size_t)srow * T_ + tix * 64 + soff];
        vr1 = *(const int4*)&vgb[(size_t)(srow + 32) * T_ + tix * 64 + soff];
    }
    *(int4*)&KVs[sgrp][srow][soff]          = kr0;
    *(int4*)&KVs[sgrp][srow + 32][soff]     = kr1;
    *(int4*)&KVs[2 + sgrp][srow][soff]      = vr0;
    *(int4*)&KVs[2 + sgrp][srow + 32][soff] = vr1;
    __syncthreads();

    const int J = (nkt + 1) >> 1;
    for (int j = 0; j < J; ++j) {
        const int kt = 2 * j + tp;                 // my compute tile
        {
            int tix = 2 * j + sgrp + 2;            // my group's next tile
            if (tix > nkt - 1) tix = nkt - 1;      // clamped
            kr0 = *(const int4*)&kgb[(size_t)(tix * 64 + srow) * HS_ + soff];
            kr1 = *(const int4*)&kgb[(size_t)(tix * 64 + srow + 32) * HS_ + soff];
            vr0 = *(const int4*)&vgb[(size_t)srow * T_ + tix * 64 + soff];
            vr1 = *(const int4*)&vgb[(size_t)(srow + 32) * T_ + tix * 64 + soff];
        }

        if (kt < nkt) {
            const int k0  = kt * 64;
            const int ks0 = h * 32;
            f32x4 st0 = {0.f,0.f,0.f,0.f}, st1 = st0;
            {
                bf16x8 ka;
                ka  = *(const bf16x8*)&KVs[tp][ks0 + n15][g * 8];
                st0 = __builtin_amdgcn_mfma_f32_16x16x32_bf16(ka, qf0, st0, 0, 0, 0);
                ka  = *(const bf16x8*)&KVs[tp][ks0 + n15][g * 8 + 32];
                st0 = __builtin_amdgcn_mfma_f32_16x16x32_bf16(ka, qf1, st0, 0, 0, 0);
                ka  = *(const bf16x8*)&KVs[tp][ks0 + 16 + n15][g * 8];
                st1 = __builtin_amdgcn_mfma_f32_16x16x32_bf16(ka, qf0, st1, 0, 0, 0);
                ka  = *(const bf16x8*)&KVs[tp][ks0 + 16 + n15][g * 8 + 32];
                st1 = __builtin_amdgcn_mfma_f32_16x16x32_bf16(ka, qf1, st1, 0, 0, 0);
            }

            // ---- causal mask: only the diagonal tile needs it ----
            if (kt == nkt - 1) {
                const int kb = k0 + h * 32 + g4;
#pragma unroll
                for (int r = 0; r < 4; ++r) {
                    if (kb + r      > qrow) st0[r] = -INFINITY;
                    if (kb + 16 + r > qrow) st1[r] = -INFINITY;
                }
            }

            // ---- static softmax: p = exp2(S) (scale folded into 1/l) ----
            float p[8];
#pragma unroll
            for (int r = 0; r < 4; ++r) {
                p[r]     = exp2f(st0[r]);
                p[4 + r] = exp2f(st1[r]);
            }
#pragma unroll
            for (int r = 0; r < 8; ++r) lp += p[r];

            bf16x8 pa;
#pragma unroll
            for (int r = 0; r < 4; ++r) {
                pa[r]     = (short)f2bf(p[r]);
                pa[4 + r] = (short)f2bf(p[4 + r]);
            }

            const int kvo = h * 32;
            {
                ushort4 lo, hi; bf16x8 vb;
#define PV_STEP(NT, ONT)                                                        \
                lo = *(const ushort4*)&KVs[2 + tp][(NT)*16 + n15][kvo + g4];    \
                hi = *(const ushort4*)&KVs[2 + tp][(NT)*16 + n15][kvo + 16 + g4];\
                vb[0] = (short)lo.x; vb[1] = (short)lo.y;                       \
                vb[2] = (short)lo.z; vb[3] = (short)lo.w;                       \
                vb[4] = (short)hi.x; vb[5] = (short)hi.y;                       \
                vb[6] = (short)hi.z; vb[7] = (short)hi.w;                       \
                ONT = __builtin_amdgcn_mfma_f32_16x16x32_bf16(pa, vb, ONT, 0, 0, 0);
                PV_STEP(0, o0)
                PV_STEP(1, o1)
                PV_STEP(2, o2)
                PV_STEP(3, o3)
#undef PV_STEP
            }
        }

        if (j + 1 < J) {
            __syncthreads();                 // all readers done with both bufs
            *(int4*)&KVs[sgrp][srow][soff]          = kr0;
            *(int4*)&KVs[sgrp][srow + 32][soff]     = kr1;
            *(int4*)&KVs[2 + sgrp][srow][soff]      = vr0;
            *(int4*)&KVs[2 + sgrp][srow + 32][soff] = vr1;
            __syncthreads();                 // next tiles visible
        }
    }

    // ---- deferred cross-lane l reduce (l is linear in p) ----
    float lrow = lp;
    lrow += __shfl_xor(lrow, 16);
    lrow += __shfl_xor(lrow, 32);

    // ---- 4-way merge: all partials share the (implicit) max -> plain sums ----
    __syncthreads();                          // all compute done; LDS free
    float* FS = (float*)&KVs[0][0][0];        // 9216 floats scratch
    const int pid = (tp << 1) | h;
    if (pid != 0) {
        float* Ob = FS + (pid - 1) * 2176 + rg * 1088;
#pragma unroll
        for (int r = 0; r < 4; ++r) {
            Ob[(g4 + r) * 68 +  0 + n15] = o0[r];
            Ob[(g4 + r) * 68 + 16 + n15] = o1[r];
            Ob[(g4 + r) * 68 + 32 + n15] = o2[r];
            Ob[(g4 + r) * 68 + 48 + n15] = o3[r];
        }
        if (g == 0)
            FS[6528 + (pid - 1) * 32 + rg * 16 + n15] = lrow;
    }
    __syncthreads();
    if (pid == 0) {
        float l1 = FS[6528 +  0 + rg * 16 + n15];
        float l2 = FS[6528 + 32 + rg * 16 + n15];
        float l3 = FS[6528 + 64 + rg * 16 + n15];
        float invl = 1.0f / (lrow + l1 + l2 + l3);   // > 0: pid0 covers diagonal
        const float* O1s = FS;
        const float* O2s = FS + 2176;
        const float* O3s = FS + 4352;
#pragma unroll
        for (int r = 0; r < 4; ++r) {
            float ir = __shfl(invl, g4 + r);
            const int base = rg * 1088 + (g4 + r) * 68 + n15;
            float* yr = &y[((size_t)b * T_ + qq0 + g4 + r) * HS_];
            yr[ 0 + n15] = (o0[r] + O1s[base]      + O2s[base]      + O3s[base]     ) * ir;
            yr[16 + n15] = (o1[r] + O1s[base + 16] + O2s[base + 16] + O3s[base + 16]) * ir;
            yr[32 + n15] = (o2[r] + O1s[base + 32] + O2s[base + 32] + O3s[base + 32]) * ir;
            yr[48 + n15] = (o3[r] + O1s[base + 48] + O2s[base + 48] + O3s[base + 48]) * ir;
        }
    }
}

extern "C" void kernel_launch(void* const* d_in, const int* in_sizes, int n_in,
                              void* d_out, int out_size, void* d_ws, size_t ws_size,
                              hipStream_t stream)
{
    const float* x  = (const float*)d_in[0];
    const float* Wq = (const float*)d_in[1];
    const float* Wk = (const float*)d_in[2];
    const float* Wv = (const float*)d_in[3];

    unsigned short* qbf  = (unsigned short*)d_ws;                 // [B,T,64] bf16 (prescaled, log2e)
    unsigned short* kbf  = qbf + (size_t)MTOT * HS_;              // [B,T,64] bf16
    unsigned short* vtbf = kbf + (size_t)MTOT * HS_;              // [B,64,T] bf16
    unsigned short* Wf   = vtbf + (size_t)MTOT * HS_;             // [384 chunks][64][8] bf16

    cast_w_kernel<<<96, 256, 0, stream>>>(Wq, Wk, Wv, Wf);
    proj_gemm<<<256, 512, 0, stream>>>(x, Wf, qbf, kbf, vtbf);
    attn_kernel<<<dim3(64, B_), 512, 0, stream>>>(qbf, kbf, vtbf, (float*)d_out);
}

// Round 21
// 42.781 us; speedup vs baseline: 3.7207x; 1.0144x over previous
//
#include <hip/hip_runtime.h>
#include <hip/hip_bf16.h>
#include <math.h>

#define B_   8
#define T_   2048
#define C_   1024
#define HS_  64
#define MTOT (B_*T_)          // 16384 rows

typedef __attribute__((ext_vector_type(8))) short bf16x8;           // MFMA A/B
typedef __attribute__((ext_vector_type(4))) float f32x4;            // MFMA C/D
typedef __attribute__((ext_vector_type(8))) unsigned short u16x8;   // 16B store

static __device__ __forceinline__ unsigned short f2bf(float f) {
    __hip_bfloat16 h = __float2bfloat16(f);
    return *reinterpret_cast<unsigned short*>(&h);
}

// ---------------------------------------------------------------------------
// Kernel 0: cast W -> bf16 in FRAGMENT ORDER Wf (validated r19):
// chunk (fg, kc, kk) of 64 lanes x 16B, lane l holds
//   Wt[(fg/3)*48 + (fg%3)*16 + (l&15)][kc*64 + kk*32 + (l>>4)*8 .. +7].
// Q section pre-scaled by C^-0.5 * log2(e).
// ---------------------------------------------------------------------------
__global__ __launch_bounds__(256) void cast_w_kernel(
    const float* __restrict__ Wq, const float* __restrict__ Wk,
    const float* __restrict__ Wv, unsigned short* __restrict__ Wf)
{
    const int gtid  = blockIdx.x * 256 + threadIdx.x;   // [0, 24576)
    const int lane  = gtid & 63;
    const int chunk = gtid >> 6;                        // [0, 384)
    const int kk    = chunk & 1;
    const int kc    = (chunk >> 1) & 15;
    const int fg    = chunk >> 5;                       // [0, 12)

    const int nrow = (fg / 3) * 48 + (fg % 3) * 16 + (lane & 15);
    const int mat  = nrow >> 6;                         // 0=q 1=k 2=v
    const int col  = nrow & 63;
    const int kb   = kc * 64 + kk * 32 + (lane >> 4) * 8;

    const float* __restrict__ W = (mat == 0) ? Wq : (mat == 1) ? Wk : Wv;
    const float s = (mat == 0) ? 0.03125f * 1.44269504f : 1.0f;  // C^-0.5 * log2e

    u16x8 o;
#pragma unroll
    for (int i = 0; i < 8; ++i)
        o[i] = f2bf(W[(size_t)(kb + i) * HS_ + col] * s);
    *(u16x8*)&Wf[(size_t)gtid * 8] = o;
}

// ---------------------------------------------------------------------------
// Kernel 1: FUSED QKV projection, bf16 MFMA, B-direct-from-L2 Wf (validated
// r19).  NEW: M-tile 64 -> 32 rows, grid 512 x 256 threads (4 waves, cg=wv)
// -> 2 blocks/CU = 4 waves/SIMD (was 2).  Per-wave work shape identical
// (2x3 frags, same staging bytes/thread, same Wf reads).  Epilogue scratch
// explicitly sized: Cqk [32][136]=4352 <= 4608 u16 (Als); VtrS[64][40]
// (80 B rows, int4-aligned).
// ---------------------------------------------------------------------------
__global__ __launch_bounds__(256) void proj_gemm(
    const float* __restrict__ x, const unsigned short* __restrict__ Wf,
    unsigned short* __restrict__ qbf, unsigned short* __restrict__ kbf,
    unsigned short* __restrict__ vtbf)
{
    __shared__ unsigned short Als[2][32][72];    // A tile [row][k] (4608 u16)
    __shared__ unsigned short VtrS[64][40];      // epilogue v scratch (2560 u16)

    const int tid  = threadIdx.x;
    const int lane = tid & 63;
    const int wv   = tid >> 6;        // 0..3
    const int cg   = wv;              // col group: cols cg*48 .. +47
    const int g    = lane >> 4;
    const int n15  = lane & 15;
    const int g4   = g * 4;
    const int m0   = blockIdx.x * 32;

    const int srow = tid >> 3;        // 0..31
    const int seg  = (tid & 7) * 8;
    const float* __restrict__ xrow = &x[(size_t)(m0 + srow) * C_ + seg];
    // per-wave Wf bases (ushort index): fragment rows cg*3+{0,1,2}
    const unsigned short* __restrict__ wf0 = &Wf[(size_t)((cg*3+0)*32*64 + lane)*8];
    const unsigned short* __restrict__ wf1 = &Wf[(size_t)((cg*3+1)*32*64 + lane)*8];
    const unsigned short* __restrict__ wf2 = &Wf[(size_t)((cg*3+2)*32*64 + lane)*8];

    f32x4 acc[2][3];
#pragma unroll
    for (int i = 0; i < 2; ++i)
#pragma unroll
        for (int j = 0; j < 3; ++j) acc[i][j] = (f32x4){0.f, 0.f, 0.f, 0.f};

    float4 a0E, a1E, a0O, a1O;                 // A prefetch (named, depth 2)
    bf16x8 bE00, bE10, bE20, bE01, bE11, bE21; // B frags, even set (kk0, kk1)
    bf16x8 bO00, bO10, bO20, bO01, bO11, bO21; // B frags, odd set

#define LOAD_A(KC, A0, A1)                                              \
    do {                                                                \
        A0 = *(const float4*)&xrow[(KC) * 64 + 0];                      \
        A1 = *(const float4*)&xrow[(KC) * 64 + 4];                      \
    } while (0)

#define LOAD_BF(KC, B00, B10, B20, B01, B11, B21)                       \
    do {                                                                \
        const size_t c0 = (size_t)(KC) * 1024;   /* (KC*2 chunks)*512 */\
        B00 = *(const bf16x8*)&wf0[c0];                                 \
        B10 = *(const bf16x8*)&wf1[c0];                                 \
        B20 = *(const bf16x8*)&wf2[c0];                                 \
        B01 = *(const bf16x8*)&wf0[c0 + 512];                           \
        B11 = *(const bf16x8*)&wf1[c0 + 512];                           \
        B21 = *(const bf16x8*)&wf2[c0 + 512];                           \
    } while (0)

#define WRITE_A(BUF, A0, A1)                                            \
    do {                                                                \
        u16x8 v0;                                                       \
        v0[0]=f2bf((A0).x); v0[1]=f2bf((A0).y);                         \
        v0[2]=f2bf((A0).z); v0[3]=f2bf((A0).w);                         \
        v0[4]=f2bf((A1).x); v0[5]=f2bf((A1).y);                         \
        v0[6]=f2bf((A1).z); v0[7]=f2bf((A1).w);                         \
        *(u16x8*)&Als[BUF][srow][seg] = v0;                             \
    } while (0)

#define COMPUTE(BUF, B00, B10, B20, B01, B11, B21)                                         \
    do {                                                                                   \
        bf16x8 fa0 = *(const bf16x8*)&Als[BUF][n15][g * 8];                                \
        bf16x8 fa1 = *(const bf16x8*)&Als[BUF][16 + n15][g * 8];                           \
        acc[0][0] = __builtin_amdgcn_mfma_f32_16x16x32_bf16(fa0, B00, acc[0][0], 0, 0, 0); \
        acc[0][1] = __builtin_amdgcn_mfma_f32_16x16x32_bf16(fa0, B10, acc[0][1], 0, 0, 0); \
        acc[0][2] = __builtin_amdgcn_mfma_f32_16x16x32_bf16(fa0, B20, acc[0][2], 0, 0, 0); \
        acc[1][0] = __builtin_amdgcn_mfma_f32_16x16x32_bf16(fa1, B00, acc[1][0], 0, 0, 0); \
        acc[1][1] = __builtin_amdgcn_mfma_f32_16x16x32_bf16(fa1, B10, acc[1][1], 0, 0, 0); \
        acc[1][2] = __builtin_amdgcn_mfma_f32_16x16x32_bf16(fa1, B20, acc[1][2], 0, 0, 0); \
        fa0 = *(const bf16x8*)&Als[BUF][n15][32 + g * 8];                                  \
        fa1 = *(const bf16x8*)&Als[BUF][16 + n15][32 + g * 8];                             \
        acc[0][0] = __builtin_amdgcn_mfma_f32_16x16x32_bf16(fa0, B01, acc[0][0], 0, 0, 0); \
        acc[0][1] = __builtin_amdgcn_mfma_f32_16x16x32_bf16(fa0, B11, acc[0][1], 0, 0, 0); \
        acc[0][2] = __builtin_amdgcn_mfma_f32_16x16x32_bf16(fa0, B21, acc[0][2], 0, 0, 0); \
        acc[1][0] = __builtin_amdgcn_mfma_f32_16x16x32_bf16(fa1, B01, acc[1][0], 0, 0, 0); \
        acc[1][1] = __builtin_amdgcn_mfma_f32_16x16x32_bf16(fa1, B11, acc[1][1], 0, 0, 0); \
        acc[1][2] = __builtin_amdgcn_mfma_f32_16x16x32_bf16(fa1, B21, acc[1][2], 0, 0, 0); \
    } while (0)

    // prologue: A(0) -> Als[0]; A(1) in flight (odd set); B(0) -> even set
    LOAD_A(0, a0E, a1E);
    LOAD_BF(0, bE00, bE10, bE20, bE01, bE11, bE21);
    WRITE_A(0, a0E, a1E);
    LOAD_A(1, a0O, a1O);
    __syncthreads();

    const int NK = C_ / 64;           // 16 (even)
#pragma unroll 1
    for (int kc = 0; kc < NK; kc += 2) {
        // ---- even body: compute tile kc from Als[0] x bE ----
        {
            const int ka = (kc + 2 < NK) ? kc + 2 : NK - 1;
            LOAD_A(ka, a0E, a1E);
            const int kb = (kc + 1 < NK) ? kc + 1 : NK - 1;
            LOAD_BF(kb, bO00, bO10, bO20, bO01, bO11, bO21);
            COMPUTE(0, bE00, bE10, bE20, bE01, bE11, bE21);
            __syncthreads();                      // readers done with Als[1]
            WRITE_A(1, a0O, a1O);                 // tile kc+1 (loaded prev odd)
            __syncthreads();
        }
        // ---- odd body: compute tile kc+1 from Als[1] x bO ----
        {
            const int ka = (kc + 3 < NK) ? kc + 3 : NK - 1;
            LOAD_A(ka, a0O, a1O);
            const int kb = (kc + 2 < NK) ? kc + 2 : NK - 1;
            LOAD_BF(kb, bE00, bE10, bE20, bE01, bE11, bE21);
            COMPUTE(1, bO00, bO10, bO20, bO01, bO11, bO21);
            if (kc + 2 < NK) {
                __syncthreads();                  // readers done with Als[0]
                WRITE_A(0, a0E, a1E);             // tile kc+2
                __syncthreads();
            }
        }
    }
#undef LOAD_A
#undef LOAD_BF
#undef WRITE_A
#undef COMPUTE

    // ---- epilogue: Cqk [32][136]=4352 u16 in Als (<=4608); v in VtrS ----
    __syncthreads();
    unsigned short* Cqk = &Als[0][0][0];
    unsigned short* Vtr = &VtrS[0][0];              // [64][40], 80B rows

#pragma unroll
    for (int i = 0; i < 2; ++i)
#pragma unroll
        for (int j = 0; j < 3; ++j) {
            const int gcol = cg * 48 + j * 16 + n15;
            const int row0 = i * 16 + g4;           // token rows 0..31
            if (gcol < 128) {
#pragma unroll
                for (int r = 0; r < 4; ++r)
                    Cqk[(size_t)(row0 + r) * 136 + gcol] = f2bf(acc[i][j][r]);
            } else {
                ushort4 o;
                o.x = f2bf(acc[i][j][0]); o.y = f2bf(acc[i][j][1]);
                o.z = f2bf(acc[i][j][2]); o.w = f2bf(acc[i][j][3]);
                *(ushort4*)&Vtr[(size_t)(gcol - 128) * 40 + row0] = o;
            }
        }
    __syncthreads();

    // q/k stores: 2 mats x 32 rows x 64 cols / 8 = 512 int4 chunks, 2/thread
#pragma unroll
    for (int p = 0; p < 2; ++p) {
        const int flat = tid + p * 256;
        const int mat  = flat >> 8;          // 0=q, 1=k
        const int r32  = (flat >> 3) & 31;
        const int sg   = (flat & 7) * 8;
        unsigned short* __restrict__ dst = mat ? kbf : qbf;
        *(int4*)&dst[(size_t)(m0 + r32) * HS_ + sg] =
            *(const int4*)&Cqk[(size_t)r32 * 136 + mat * 64 + sg];
    }
    // v stores: 64 hs x 32 tok / 8 = 256 int4 chunks, 1/thread
    {
        const int b    = m0 >> 11;
        const int t0   = m0 & 2047;
        const int hs   = tid >> 2;           // 0..63
        const int tseg = (tid & 3) * 8;      // 0,8,16,24
        *(int4*)&vtbf[((size_t)b * HS_ + hs) * T_ + t0 + tseg] =
            *(const int4*)&Vtr[(size_t)hs * 40 + tseg];
    }
}

// ---------------------------------------------------------------------------
// Kernel 2: causal flash attention, bf16 MFMA — r19 validated structure:
// static softmax p = exp2(S), deferred l-reduce, diagonal-only mask,
// grid (64,8) complementary swizzle.  Unchanged.
// ---------------------------------------------------------------------------
__global__ __launch_bounds__(512) void attn_kernel(
    const unsigned short* __restrict__ qbf,
    const unsigned short* __restrict__ kbf,
    const unsigned short* __restrict__ vtbf,
    float* __restrict__ y)
{
    __shared__ unsigned short KVs[4][64][72];   // [0..1]=K bufs, [2..3]=V bufs

    const int tid  = threadIdx.x;
    const int lane = tid & 63;
    const int wv   = tid >> 6;        // 0..7
    const int rg   = wv & 1;          // query 16-group
    const int h    = (wv >> 1) & 1;   // KV 32-half within tile
    const int tp   = wv >> 2;         // tile parity group
    const int g    = lane >> 4;
    const int n15  = lane & 15;
    const int g4   = g * 4;
    const int b    = blockIdx.y;
    const size_t qkoff = (size_t)b * T_ * HS_;
    const size_t voff  = (size_t)b * HS_ * T_;

    const int sgrp = tid >> 8;        // staging group == its waves' tp
    const int st   = tid & 255;
    const int srow = st >> 3;         // 0..31
    const int soff = (st & 7) * 8;

    const unsigned short* __restrict__ kgb = &kbf[qkoff];
    const unsigned short* __restrict__ vgb = &vtbf[voff];

    // complementary swizzle: co-resident pair (x,y) & (x,y+4) sums to 33 tiles
    const int qbi  = (blockIdx.y < 4) ? (int)blockIdx.x : 63 - (int)blockIdx.x;
    const int q0   = qbi * 32;
    const int qq0  = q0 + rg * 16;
    const int qrow = qq0 + n15;
    const int nkt  = (qbi >> 1) + 1;

    bf16x8 qf0 = *(const bf16x8*)&qbf[qkoff + (size_t)qrow * HS_ + g * 8];
    bf16x8 qf1 = *(const bf16x8*)&qbf[qkoff + (size_t)qrow * HS_ + g * 8 + 32];

    f32x4 o0 = {0.f,0.f,0.f,0.f}, o1 = o0, o2 = o0, o3 = o0;
    float lp = 0.f;                   // per-lane l partial (reduced after loop)

    int4 kr0, kr1, vr0, vr1;
    // prologue: group sgrp stages tile min(sgrp, nkt-1) into buffer sgrp
    {
        int tix = (sgrp < nkt) ? sgrp : nkt - 1;
        kr0 = *(const int4*)&kgb[(size_t)(tix * 64 + srow) * HS_ + soff];
        kr1 = *(const int4*)&kgb[(size_t)(tix * 64 + srow + 32) * HS_ + soff];
        vr0 = *(const int4*)&vgb[(size_t)srow * T_ + tix * 64 + soff];
        vr1 = *(const int4*)&vgb[(size_t)(srow + 32) * T_ + tix * 64 + soff];
    }
    *(int4*)&KVs[sgrp][srow][soff]          = kr0;
    *(int4*)&KVs[sgrp][srow + 32][soff]     = kr1;
    *(int4*)&KVs[2 + sgrp][srow][soff]      = vr0;
    *(int4*)&KVs[2 + sgrp][srow + 32][soff] = vr1;
    __syncthreads();

    const int J = (nkt + 1) >> 1;
    for (int j = 0; j < J; ++j) {
        const int kt = 2 * j + tp;                 // my compute tile
        {
            int tix = 2 * j + sgrp + 2;            // my group's next tile
            if (tix > nkt - 1) tix = nkt - 1;      // clamped
            kr0 = *(const int4*)&kgb[(size_t)(tix * 64 + srow) * HS_ + soff];
            kr1 = *(const int4*)&kgb[(size_t)(tix * 64 + srow + 32) * HS_ + soff];
            vr0 = *(const int4*)&vgb[(size_t)srow * T_ + tix * 64 + soff];
            vr1 = *(const int4*)&vgb[(size_t)(srow + 32) * T_ + tix * 64 + soff];
        }

        if (kt < nkt) {
            const int k0  = kt * 64;
            const int ks0 = h * 32;
            f32x4 st0 = {0.f,0.f,0.f,0.f}, st1 = st0;
            {
                bf16x8 ka;
                ka  = *(const bf16x8*)&KVs[tp][ks0 + n15][g * 8];
                st0 = __builtin_amdgcn_mfma_f32_16x16x32_bf16(ka, qf0, st0, 0, 0, 0);
                ka  = *(const bf16x8*)&KVs[tp][ks0 + n15][g * 8 + 32];
                st0 = __builtin_amdgcn_mfma_f32_16x16x32_bf16(ka, qf1, st0, 0, 0, 0);
                ka  = *(const bf16x8*)&KVs[tp][ks0 + 16 + n15][g * 8];
                st1 = __builtin_amdgcn_mfma_f32_16x16x32_bf16(ka, qf0, st1, 0, 0, 0);
                ka  = *(const bf16x8*)&KVs[tp][ks0 + 16 + n15][g * 8 + 32];
                st1 = __builtin_amdgcn_mfma_f32_16x16x32_bf16(ka, qf1, st1, 0, 0, 0);
            }

            // ---- causal mask: only the diagonal tile needs it ----
            if (kt == nkt - 1) {
                const int kb = k0 + h * 32 + g4;
#pragma unroll
                for (int r = 0; r < 4; ++r) {
                    if (kb + r      > qrow) st0[r] = -INFINITY;
                    if (kb + 16 + r > qrow) st1[r] = -INFINITY;
                }
            }

            // ---- static softmax: p = exp2(S) (scale folded into 1/l) ----
            float p[8];
#pragma unroll
            for (int r = 0; r < 4; ++r) {
                p[r]     = exp2f(st0[r]);
                p[4 + r] = exp2f(st1[r]);
            }
#pragma unroll
            for (int r = 0; r < 8; ++r) lp += p[r];

            bf16x8 pa;
#pragma unroll
            for (int r = 0; r < 4; ++r) {
                pa[r]     = (short)f2bf(p[r]);
                pa[4 + r] = (short)f2bf(p[4 + r]);
            }

            const int kvo = h * 32;
            {
                ushort4 lo, hi; bf16x8 vb;
#define PV_STEP(NT, ONT)                                                        \
                lo = *(const ushort4*)&KVs[2 + tp][(NT)*16 + n15][kvo + g4];    \
                hi = *(const ushort4*)&KVs[2 + tp][(NT)*16 + n15][kvo + 16 + g4];\
                vb[0] = (short)lo.x; vb[1] = (short)lo.y;                       \
                vb[2] = (short)lo.z; vb[3] = (short)lo.w;                       \
                vb[4] = (short)hi.x; vb[5] = (short)hi.y;                       \
                vb[6] = (short)hi.z; vb[7] = (short)hi.w;                       \
                ONT = __builtin_amdgcn_mfma_f32_16x16x32_bf16(pa, vb, ONT, 0, 0, 0);
                PV_STEP(0, o0)
                PV_STEP(1, o1)
                PV_STEP(2, o2)
                PV_STEP(3, o3)
#undef PV_STEP
            }
        }

        if (j + 1 < J) {
            __syncthreads();                 // all readers done with both bufs
            *(int4*)&KVs[sgrp][srow][soff]          = kr0;
            *(int4*)&KVs[sgrp][srow + 32][soff]     = kr1;
            *(int4*)&KVs[2 + sgrp][srow][soff]      = vr0;
            *(int4*)&KVs[2 + sgrp][srow + 32][soff] = vr1;
            __syncthreads();                 // next tiles visible
        }
    }

    // ---- deferred cross-lane l reduce (l is linear in p) ----
    float lrow = lp;
    lrow += __shfl_xor(lrow, 16);
    lrow += __shfl_xor(lrow, 32);

    // ---- 4-way merge: all partials share the (implicit) max -> plain sums ----
    __syncthreads();                          // all compute done; LDS free
    float* FS = (float*)&KVs[0][0][0];        // 9216 floats scratch
    const int pid = (tp << 1) | h;
    if (pid != 0) {
        float* Ob = FS + (pid - 1) * 2176 + rg * 1088;
#pragma unroll
        for (int r = 0; r < 4; ++r) {
            Ob[(g4 + r) * 68 +  0 + n15] = o0[r];
            Ob[(g4 + r) * 68 + 16 + n15] = o1[r];
            Ob[(g4 + r) * 68 + 32 + n15] = o2[r];
            Ob[(g4 + r) * 68 + 48 + n15] = o3[r];
        }
        if (g == 0)
            FS[6528 + (pid - 1) * 32 + rg * 16 + n15] = lrow;
    }
    __syncthreads();
    if (pid == 0) {
        float l1 = FS[6528 +  0 + rg * 16 + n15];
        float l2 = FS[6528 + 32 + rg * 16 + n15];
        float l3 = FS[6528 + 64 + rg * 16 + n15];
        float invl = 1.0f / (lrow + l1 + l2 + l3);   // > 0: pid0 covers diagonal
        const float* O1s = FS;
        const float* O2s = FS + 2176;
        const float* O3s = FS + 4352;
#pragma unroll
        for (int r = 0; r < 4; ++r) {
            float ir = __shfl(invl, g4 + r);
            const int base = rg * 1088 + (g4 + r) * 68 + n15;
            float* yr = &y[((size_t)b * T_ + qq0 + g4 + r) * HS_];
            yr[ 0 + n15] = (o0[r] + O1s[base]      + O2s[base]      + O3s[base]     ) * ir;
            yr[16 + n15] = (o1[r] + O1s[base + 16] + O2s[base + 16] + O3s[base + 16]) * ir;
            yr[32 + n15] = (o2[r] + O1s[base + 32] + O2s[base + 32] + O3s[base + 32]) * ir;
            yr[48 + n15] = (o3[r] + O1s[base + 48] + O2s[base + 48] + O3s[base + 48]) * ir;
        }
    }
}

extern "C" void kernel_launch(void* const* d_in, const int* in_sizes, int n_in,
                              void* d_out, int out_size, void* d_ws, size_t ws_size,
                              hipStream_t stream)
{
    const float* x  = (const float*)d_in[0];
    const float* Wq = (const float*)d_in[1];
    const float* Wk = (const float*)d_in[2];
    const float* Wv = (const float*)d_in[3];

    unsigned short* qbf  = (unsigned short*)d_ws;                 // [B,T,64] bf16 (prescaled, log2e)
    unsigned short* kbf  = qbf + (size_t)MTOT * HS_;              // [B,T,64] bf16
    unsigned short* vtbf = kbf + (size_t)MTOT * HS_;              // [B,64,T] bf16
    unsigned short* Wf   = vtbf + (size_t)MTOT * HS_;             // [384 chunks][64][8] bf16

    cast_w_kernel<<<96, 256, 0, stream>>>(Wq, Wk, Wv, Wf);
    proj_gemm<<<512, 256, 0, stream>>>(x, Wf, qbf, kbf, vtbf);
    attn_kernel<<<dim3(64, B_), 512, 0, stream>>>(qbf, kbf, vtbf, (float*)d_out);
}